// Round 6
// baseline (41180.023 us; speedup 1.0000x reference)
//
#include <hip/hip_runtime.h>
#include <hip/hip_bf16.h>

#define BB 64
#define TT 2048
#define HH 256
#define H4 1024
#define NC 10

__device__ __forceinline__ float sigmoidf_(float x) {
    return 1.0f / (1.0f + expf(-x));
}

// ---------------------------------------------------------------------------
// gx GEMM: gx[tc][b][n] = sum_k A[b][t0+tc][k] * W[n][k] + bias1[n] + bias2[n]
// A row stride = Tstride (TT for x, TC for h1 chunk). 128x128 tiles, 8x8/thr.
// ---------------------------------------------------------------------------
__global__ __launch_bounds__(256, 2)
void gemm_gx(const float* __restrict__ A, const float* __restrict__ W,
             const float* __restrict__ bias1, const float* __restrict__ bias2,
             float* __restrict__ gx, int t0, int Tstride)
{
    __shared__ float As[8][132];
    __shared__ float Bs[8][132];
    const int tid = threadIdx.x;
    const int m0 = blockIdx.y * 128, n0 = blockIdx.x * 128;
    const int tx = tid & 15, ty = tid >> 4;

    float acc[8][8];
#pragma unroll
    for (int i = 0; i < 8; i++)
#pragma unroll
        for (int j = 0; j < 8; j++) acc[i][j] = 0.f;

    const int mL = tid >> 1, half = tid & 1;
    const int gm = m0 + mL;
    const int b = gm & 63, tc = gm >> 6;
    const float* arow = A + ((size_t)b * Tstride + t0 + tc) * 256;
    const float* brow = W + (size_t)(n0 + mL) * 256;

    for (int k0 = 0; k0 < 256; k0 += 8) {
        float4 av = *(const float4*)(arow + k0 + half * 4);
        float4 bv = *(const float4*)(brow + k0 + half * 4);
        __syncthreads();
        As[half * 4 + 0][mL] = av.x; As[half * 4 + 1][mL] = av.y;
        As[half * 4 + 2][mL] = av.z; As[half * 4 + 3][mL] = av.w;
        Bs[half * 4 + 0][mL] = bv.x; Bs[half * 4 + 1][mL] = bv.y;
        Bs[half * 4 + 2][mL] = bv.z; Bs[half * 4 + 3][mL] = bv.w;
        __syncthreads();
#pragma unroll
        for (int k = 0; k < 8; k++) {
            float a[8], w[8];
            *(float4*)&a[0] = *(const float4*)&As[k][ty * 8];
            *(float4*)&a[4] = *(const float4*)&As[k][ty * 8 + 4];
            *(float4*)&w[0] = *(const float4*)&Bs[k][tx * 8];
            *(float4*)&w[4] = *(const float4*)&Bs[k][tx * 8 + 4];
#pragma unroll
            for (int i = 0; i < 8; i++)
#pragma unroll
                for (int j = 0; j < 8; j++) acc[i][j] += a[i] * w[j];
        }
    }
#pragma unroll
    for (int i = 0; i < 8; i++) {
        int m = m0 + ty * 8 + i;
        int bb = m & 63, tcc = m >> 6;
#pragma unroll
        for (int j = 0; j < 8; j++) {
            int n = n0 + tx * 8 + j;
            gx[((size_t)tcc * BB + bb) * H4 + n] = acc[i][j] + bias1[n] + bias2[n];
        }
    }
}

// ---------------------------------------------------------------------------
// Weight transpose: out[k][r] = in[r][k], in = [1024][256]. grid (16,4), 256 thr.
// ---------------------------------------------------------------------------
__global__ void transpose_w(const float* __restrict__ in, float* __restrict__ out)
{
    __shared__ float tile[64][65];
    const int tid = threadIdx.x;
    const int lx = tid & 63, ly = tid >> 6;       // 64 x 4
    const int r0 = blockIdx.x * 64, k0 = blockIdx.y * 64;
#pragma unroll
    for (int j = 0; j < 16; j++) {
        int rr = ly * 16 + j;
        tile[rr][lx] = in[(size_t)(r0 + rr) * 256 + k0 + lx];
    }
    __syncthreads();
#pragma unroll
    for (int j = 0; j < 16; j++) {
        int kk = ly * 16 + j;
        out[(size_t)(k0 + kk) * 1024 + r0 + lx] = tile[lx][kk];
    }
}

// ---------------------------------------------------------------------------
// Batch-parallel LSTM recurrence: one WG per batch. ZERO cross-WG sync.
// Wt = W_hh transposed [256][1024] (streams from L2 each step, stays resident).
// gx = [TC][64][1024] precomputed input contribution (incl. both biases).
// Thread t owns gate-rows 4t..4t+3 (gate g=t>>6, units 4*(t&63)..+3), then
// after LDS gate exchange, thread t owns unit t's c/h.
// ---------------------------------------------------------------------------
__global__ __launch_bounds__(256, 1)
void rec_batch(const float* __restrict__ gx, const float* __restrict__ Wt,
               float* __restrict__ hst, float* __restrict__ cst,
               float* __restrict__ hseq, int TC, int writeH)
{
    __shared__ float hl[2][260];      // double-buffered h (2 syncs/step)
    __shared__ float pre[4][256];     // gate pre-activations
    const int b = blockIdx.x, t = threadIdx.x;
    const int g = t >> 6, ub = (t & 63) * 4;

    float c = cst[b * HH + t];
    hl[0][t] = hst[b * HH + t];
    __syncthreads();

    const float* wbase = Wt + 4 * t;  // this thread's 4 columns
    int p = 0;

    for (int tc = 0; tc < TC; tc++) {
        const float* gp = gx + ((size_t)tc * BB + b) * H4 + 4 * t;
        float4 acc = *(const float4*)gp;   // init with gx (incl. biases)
        const float* hp = &hl[p][0];
#pragma unroll 4
        for (int k = 0; k < 256; k += 4) {
            float4 h4 = *(const float4*)(hp + k);
            float4 w0 = *(const float4*)(wbase + (size_t)(k + 0) * H4);
            float4 w1 = *(const float4*)(wbase + (size_t)(k + 1) * H4);
            float4 w2 = *(const float4*)(wbase + (size_t)(k + 2) * H4);
            float4 w3 = *(const float4*)(wbase + (size_t)(k + 3) * H4);
            acc.x += w0.x * h4.x + w1.x * h4.y + w2.x * h4.z + w3.x * h4.w;
            acc.y += w0.y * h4.x + w1.y * h4.y + w2.y * h4.z + w3.y * h4.w;
            acc.z += w0.z * h4.x + w1.z * h4.y + w2.z * h4.z + w3.z * h4.w;
            acc.w += w0.w * h4.x + w1.w * h4.y + w2.w * h4.z + w3.w * h4.w;
        }
        *(float4*)&pre[g][ub] = acc;
        __syncthreads();                   // pre ready; all hl[p] reads done
        float pi = pre[0][t], pf = pre[1][t], pg = pre[2][t], po = pre[3][t];
        float ig = sigmoidf_(pi), fg = sigmoidf_(pf);
        float gg = tanhf(pg),     og = sigmoidf_(po);
        c = fg * c + ig * gg;
        float h = og * tanhf(c);
        hl[p ^ 1][t] = h;
        if (writeH) hseq[((size_t)b * TC + tc) * HH + t] = h;
        p ^= 1;
        __syncthreads();                   // new h ready; pre safe to overwrite
    }

    cst[b * HH + t] = c;
    hst[b * HH + t] = hl[p][t];
}

// ---------------------------------------------------------------------------
__global__ void fc_kernel(const float* __restrict__ h2,
                          const float* __restrict__ Wfc,
                          const float* __restrict__ bfc,
                          float* __restrict__ out)
{
    __shared__ float hs[256];
    int b = blockIdx.x, tid = threadIdx.x;
    hs[tid] = h2[b * HH + tid];
    __syncthreads();
    if (tid < NC) {
        float s = bfc[tid];
        for (int k = 0; k < 256; k++) s += hs[k] * Wfc[tid * 256 + k];
        out[b * NC + tid] = s;
    }
}

// ---------------------------------------------------------------------------
extern "C" void kernel_launch(void* const* d_in, const int* in_sizes, int n_in,
                              void* d_out, int out_size, void* d_ws, size_t ws_size,
                              hipStream_t stream)
{
    const float* x    = (const float*)d_in[0];
    const float* Wih0 = (const float*)d_in[1];
    const float* Whh0 = (const float*)d_in[2];
    const float* bih0 = (const float*)d_in[3];
    const float* bhh0 = (const float*)d_in[4];
    const float* Wih1 = (const float*)d_in[5];
    const float* Whh1 = (const float*)d_in[6];
    const float* bih1 = (const float*)d_in[7];
    const float* bhh1 = (const float*)d_in[8];
    const float* Wfc  = (const float*)d_in[9];
    const float* bfc  = (const float*)d_in[10];

    float* ws = (float*)d_ws;

    // choose chunk size: gx chunk + h1 chunk + 2 transposed weights + states
    int TC = TT;
    while (TC > 128) {
        size_t need = ((size_t)TC * BB * H4 + (size_t)TC * BB * HH +
                       2 * (size_t)HH * H4 + 4 * (size_t)BB * HH + 1024) * 4;
        if (need <= ws_size) break;
        TC >>= 1;
    }

    float* gxb = ws;                                    // [TC][64][1024]
    float* h1c = gxb + (size_t)TC * BB * H4;            // [64][TC][256]
    float* wt0 = h1c + (size_t)TC * BB * HH;            // [256][1024]
    float* wt1 = wt0 + (size_t)HH * H4;
    float* hs1 = wt1 + (size_t)HH * H4;                 // 4 x [64][256] states
    float* cs1 = hs1 + BB * HH;
    float* hs2 = cs1 + BB * HH;
    float* cs2 = hs2 + BB * HH;

    // zero states each launch (graph-replay safe)
    hipMemsetAsync(hs1, 0, (size_t)4 * BB * HH * 4, stream);

    // transpose recurrent weights once per launch
    transpose_w<<<dim3(16, 4), 256, 0, stream>>>(Whh0, wt0);
    transpose_w<<<dim3(16, 4), 256, 0, stream>>>(Whh1, wt1);

    const int nchunk = TT / TC;
    for (int ch = 0; ch < nchunk; ch++) {
        int t0 = ch * TC;
        dim3 gg(8, TC * 64 / 128);
        // layer 1: input GEMM on x, then batch-parallel recurrence
        gemm_gx<<<gg, 256, 0, stream>>>(x, Wih0, bih0, bhh0, gxb, t0, TT);
        rec_batch<<<BB, 256, 0, stream>>>(gxb, wt0, hs1, cs1, h1c, TC, 1);
        // layer 2: input GEMM on h1 chunk (reuses gx buffer), then recurrence
        gemm_gx<<<gg, 256, 0, stream>>>(h1c, Wih1, bih1, bhh1, gxb, 0, TC);
        rec_batch<<<BB, 256, 0, stream>>>(gxb, wt1, hs2, cs2, nullptr, TC, 0);
    }

    fc_kernel<<<BB, 256, 0, stream>>>(hs2, Wfc, bfc, (float*)d_out);
}

// Round 7
// 23656.880 us; speedup vs baseline: 1.7407x; 1.7407x over previous
//
#include <hip/hip_runtime.h>
#include <hip/hip_bf16.h>

#define BB 64
#define TT 2048
#define HH 256
#define H4 1024
#define NC 10

typedef _Float16 half2v __attribute__((ext_vector_type(2)));

__device__ __forceinline__ float sigmoidf_(float x) {
    return 1.0f / (1.0f + expf(-x));
}

__device__ __forceinline__ float fdot2_(unsigned wu, half2v hv, float acc) {
#if __has_builtin(__builtin_amdgcn_fdot2)
    return __builtin_amdgcn_fdot2(__builtin_bit_cast(half2v, wu), hv, acc, false);
#else
    half2v w = __builtin_bit_cast(half2v, wu);
    return acc + (float)w[0] * (float)hv[0] + (float)w[1] * (float)hv[1];
#endif
}

// ---------------------------------------------------------------------------
// gx GEMM: gx[tc][b][n] = sum_k A[b][t0+tc][k] * W[n][k] + bias1[n] + bias2[n]
// A row stride = Tstride (TT for x, TC for h1 chunk). 128x128 tiles, 8x8/thr.
// ---------------------------------------------------------------------------
__global__ __launch_bounds__(256, 2)
void gemm_gx(const float* __restrict__ A, const float* __restrict__ W,
             const float* __restrict__ bias1, const float* __restrict__ bias2,
             float* __restrict__ gx, int t0, int Tstride)
{
    __shared__ float As[8][132];
    __shared__ float Bs[8][132];
    const int tid = threadIdx.x;
    const int m0 = blockIdx.y * 128, n0 = blockIdx.x * 128;
    const int tx = tid & 15, ty = tid >> 4;

    float acc[8][8];
#pragma unroll
    for (int i = 0; i < 8; i++)
#pragma unroll
        for (int j = 0; j < 8; j++) acc[i][j] = 0.f;

    const int mL = tid >> 1, half = tid & 1;
    const int gm = m0 + mL;
    const int b = gm & 63, tc = gm >> 6;
    const float* arow = A + ((size_t)b * Tstride + t0 + tc) * 256;
    const float* brow = W + (size_t)(n0 + mL) * 256;

    for (int k0 = 0; k0 < 256; k0 += 8) {
        float4 av = *(const float4*)(arow + k0 + half * 4);
        float4 bv = *(const float4*)(brow + k0 + half * 4);
        __syncthreads();
        As[half * 4 + 0][mL] = av.x; As[half * 4 + 1][mL] = av.y;
        As[half * 4 + 2][mL] = av.z; As[half * 4 + 3][mL] = av.w;
        Bs[half * 4 + 0][mL] = bv.x; Bs[half * 4 + 1][mL] = bv.y;
        Bs[half * 4 + 2][mL] = bv.z; Bs[half * 4 + 3][mL] = bv.w;
        __syncthreads();
#pragma unroll
        for (int k = 0; k < 8; k++) {
            float a[8], w[8];
            *(float4*)&a[0] = *(const float4*)&As[k][ty * 8];
            *(float4*)&a[4] = *(const float4*)&As[k][ty * 8 + 4];
            *(float4*)&w[0] = *(const float4*)&Bs[k][tx * 8];
            *(float4*)&w[4] = *(const float4*)&Bs[k][tx * 8 + 4];
#pragma unroll
            for (int i = 0; i < 8; i++)
#pragma unroll
                for (int j = 0; j < 8; j++) acc[i][j] += a[i] * w[j];
        }
    }
#pragma unroll
    for (int i = 0; i < 8; i++) {
        int m = m0 + ty * 8 + i;
        int bb = m & 63, tcc = m >> 6;
#pragma unroll
        for (int j = 0; j < 8; j++) {
            int n = n0 + tx * 8 + j;
            gx[((size_t)tcc * BB + bb) * H4 + n] = acc[i][j] + bias1[n] + bias2[n];
        }
    }
}

// ---------------------------------------------------------------------------
// Pack W_hh [1024][256] fp32 -> wpk[k2][tau] uint4, where component q holds
// half2( W[q*256+tau][2*k2], W[q*256+tau][2*k2+1] ).
// grid 128 (k2), 256 threads (tau). One-time; reads hit L2 after first block.
// ---------------------------------------------------------------------------
__global__ void prep_w(const float* __restrict__ W, uint4* __restrict__ out)
{
    const int k2 = blockIdx.x, t = threadIdx.x;
    unsigned q4[4];
#pragma unroll
    for (int q = 0; q < 4; q++) {
        const float* wr = W + (size_t)(q * 256 + t) * 256 + 2 * k2;
        union { _Float16 h[2]; unsigned u; } cv;
        cv.h[0] = (_Float16)wr[0];
        cv.h[1] = (_Float16)wr[1];
        q4[q] = cv.u;
    }
    out[(size_t)k2 * 256 + t] = make_uint4(q4[0], q4[1], q4[2], q4[3]);
}

// ---------------------------------------------------------------------------
// Batch-parallel recurrence, zero cross-WG sync. One WG (256 thr) per batch.
// Thread tau owns unit tau: all 4 gate rows {q*256+tau}. Weights fp16-packed:
// k2 in [0,64) register-resident (64 uint4 = 256 VGPR), k2 in [64,128)
// streamed from L2 each step (256 KB/WG/step). h kept fp16 in LDS, read as
// b128 broadcast (conflict-free). No gate exchange: c,h live in thread tau.
// ---------------------------------------------------------------------------
__global__ __launch_bounds__(256, 1)
void rec_batch_reg(const float* __restrict__ gx, const uint4* __restrict__ wpk,
                   float* __restrict__ hst, float* __restrict__ cst,
                   float* __restrict__ hseq, int TC, int writeH)
{
    __shared__ __align__(16) _Float16 hl[2][264];
    const int b = blockIdx.x, t = threadIdx.x;

    // resident weights: k2 in [0,64)
    uint4 w4[64];
#pragma unroll
    for (int k2 = 0; k2 < 64; k2++) w4[k2] = wpk[k2 * 256 + t];

    float c = cst[b * HH + t];
    float lastH = hst[b * HH + t];
    hl[0][t] = (_Float16)lastH;
    __syncthreads();

    int p = 0;
    for (int tc = 0; tc < TC; tc++) {
        const float* gp = gx + ((size_t)tc * BB + b) * H4 + t;
        float g0 = gp[0], g1 = gp[256], g2 = gp[512], g3 = gp[768];

        const uint4* hp4 = (const uint4*)&hl[p][0];   // 32 x (4 half2)
        float a0 = 0.f, a1 = 0.f, a2 = 0.f, a3 = 0.f;

        // resident half: k2 = k8*4+j, k8 in [0,16)
#pragma unroll
        for (int k8 = 0; k8 < 16; k8++) {
            uint4 hq = hp4[k8];
            half2v hv0 = __builtin_bit_cast(half2v, hq.x);
            half2v hv1 = __builtin_bit_cast(half2v, hq.y);
            half2v hv2 = __builtin_bit_cast(half2v, hq.z);
            half2v hv3 = __builtin_bit_cast(half2v, hq.w);
            a0 = fdot2_(w4[k8*4+0].x, hv0, a0);
            a1 = fdot2_(w4[k8*4+0].y, hv0, a1);
            a2 = fdot2_(w4[k8*4+0].z, hv0, a2);
            a3 = fdot2_(w4[k8*4+0].w, hv0, a3);
            a0 = fdot2_(w4[k8*4+1].x, hv1, a0);
            a1 = fdot2_(w4[k8*4+1].y, hv1, a1);
            a2 = fdot2_(w4[k8*4+1].z, hv1, a2);
            a3 = fdot2_(w4[k8*4+1].w, hv1, a3);
            a0 = fdot2_(w4[k8*4+2].x, hv2, a0);
            a1 = fdot2_(w4[k8*4+2].y, hv2, a1);
            a2 = fdot2_(w4[k8*4+2].z, hv2, a2);
            a3 = fdot2_(w4[k8*4+2].w, hv2, a3);
            a0 = fdot2_(w4[k8*4+3].x, hv3, a0);
            a1 = fdot2_(w4[k8*4+3].y, hv3, a1);
            a2 = fdot2_(w4[k8*4+3].z, hv3, a2);
            a3 = fdot2_(w4[k8*4+3].w, hv3, a3);
        }
        // streamed half: k2 in [64,128)
#pragma unroll 4
        for (int k8 = 16; k8 < 32; k8++) {
            uint4 hq = hp4[k8];
            uint4 s0 = wpk[(k8*4+0) * 256 + t];
            uint4 s1 = wpk[(k8*4+1) * 256 + t];
            uint4 s2 = wpk[(k8*4+2) * 256 + t];
            uint4 s3 = wpk[(k8*4+3) * 256 + t];
            half2v hv0 = __builtin_bit_cast(half2v, hq.x);
            half2v hv1 = __builtin_bit_cast(half2v, hq.y);
            half2v hv2 = __builtin_bit_cast(half2v, hq.z);
            half2v hv3 = __builtin_bit_cast(half2v, hq.w);
            a0 = fdot2_(s0.x, hv0, a0);
            a1 = fdot2_(s0.y, hv0, a1);
            a2 = fdot2_(s0.z, hv0, a2);
            a3 = fdot2_(s0.w, hv0, a3);
            a0 = fdot2_(s1.x, hv1, a0);
            a1 = fdot2_(s1.y, hv1, a1);
            a2 = fdot2_(s1.z, hv1, a2);
            a3 = fdot2_(s1.w, hv1, a3);
            a0 = fdot2_(s2.x, hv2, a0);
            a1 = fdot2_(s2.y, hv2, a1);
            a2 = fdot2_(s2.z, hv2, a2);
            a3 = fdot2_(s2.w, hv2, a3);
            a0 = fdot2_(s3.x, hv3, a0);
            a1 = fdot2_(s3.y, hv3, a1);
            a2 = fdot2_(s3.z, hv3, a2);
            a3 = fdot2_(s3.w, hv3, a3);
        }

        float ig = sigmoidf_(a0 + g0), fg = sigmoidf_(a1 + g1);
        float gg = tanhf(a2 + g2),     og = sigmoidf_(a3 + g3);
        c = fg * c + ig * gg;
        float h = og * tanhf(c);
        lastH = h;
        if (writeH) hseq[((size_t)b * TC + tc) * HH + t] = h;
        hl[p ^ 1][t] = (_Float16)h;
        __syncthreads();
        p ^= 1;
    }

    cst[b * HH + t] = c;
    hst[b * HH + t] = lastH;
}

// ---------------------------------------------------------------------------
__global__ void fc_kernel(const float* __restrict__ h2,
                          const float* __restrict__ Wfc,
                          const float* __restrict__ bfc,
                          float* __restrict__ out)
{
    __shared__ float hs[256];
    int b = blockIdx.x, tid = threadIdx.x;
    hs[tid] = h2[b * HH + tid];
    __syncthreads();
    if (tid < NC) {
        float s = bfc[tid];
        for (int k = 0; k < 256; k++) s += hs[k] * Wfc[tid * 256 + k];
        out[b * NC + tid] = s;
    }
}

// ---------------------------------------------------------------------------
extern "C" void kernel_launch(void* const* d_in, const int* in_sizes, int n_in,
                              void* d_out, int out_size, void* d_ws, size_t ws_size,
                              hipStream_t stream)
{
    const float* x    = (const float*)d_in[0];
    const float* Wih0 = (const float*)d_in[1];
    const float* Whh0 = (const float*)d_in[2];
    const float* bih0 = (const float*)d_in[3];
    const float* bhh0 = (const float*)d_in[4];
    const float* Wih1 = (const float*)d_in[5];
    const float* Whh1 = (const float*)d_in[6];
    const float* bih1 = (const float*)d_in[7];
    const float* bhh1 = (const float*)d_in[8];
    const float* Wfc  = (const float*)d_in[9];
    const float* bfc  = (const float*)d_in[10];

    float* ws = (float*)d_ws;

    // workspace: gx chunk + h1 chunk + 2 packed weights (128K floats ea) + states
    int TC = TT;
    while (TC > 128) {
        size_t need = ((size_t)TC * BB * H4 + (size_t)TC * BB * HH +
                       2 * 131072 + 4 * (size_t)BB * HH + 1024) * 4;
        if (need <= ws_size) break;
        TC >>= 1;
    }

    float* gxb = ws;                                    // [TC][64][1024]
    float* h1c = gxb + (size_t)TC * BB * H4;            // [64][TC][256]
    uint4* wpk0 = (uint4*)(h1c + (size_t)TC * BB * HH); // [128][256] uint4
    uint4* wpk1 = wpk0 + 128 * 256;
    float* hs1 = (float*)(wpk1 + 128 * 256);            // 4 x [64][256] states
    float* cs1 = hs1 + BB * HH;
    float* hs2 = cs1 + BB * HH;
    float* cs2 = hs2 + BB * HH;

    // zero states each launch (graph-replay safe)
    hipMemsetAsync(hs1, 0, (size_t)4 * BB * HH * 4, stream);

    // pack recurrent weights to fp16 once per launch
    prep_w<<<128, 256, 0, stream>>>(Whh0, wpk0);
    prep_w<<<128, 256, 0, stream>>>(Whh1, wpk1);

    const int nchunk = TT / TC;
    for (int ch = 0; ch < nchunk; ch++) {
        int t0 = ch * TC;
        dim3 gg(8, TC * 64 / 128);
        // layer 1
        gemm_gx<<<gg, 256, 0, stream>>>(x, Wih0, bih0, bhh0, gxb, t0, TT);
        rec_batch_reg<<<BB, 256, 0, stream>>>(gxb, wpk0, hs1, cs1, h1c, TC, 1);
        // layer 2 (input GEMM on h1 chunk, reuses gx buffer)
        gemm_gx<<<gg, 256, 0, stream>>>(h1c, Wih1, bih1, bhh1, gxb, 0, TC);
        rec_batch_reg<<<BB, 256, 0, stream>>>(gxb, wpk1, hs2, cs2, nullptr, TC, 0);
    }

    fc_kernel<<<BB, 256, 0, stream>>>(hs2, Wfc, bfc, (float*)d_out);
}